// Round 1
// baseline (284.723 us; speedup 1.0000x reference)
//
#include <hip/hip_runtime.h>
#include <hip/hip_bf16.h>
#include <math.h>
#include <stdint.h>

#define NB 4
#define NQ 100
#define NCLS 81
#define NT 20
#define NH 256
#define NW 256
#define NHW 65536
#define SCHUNK 4
#define CHUNK_PX (NHW / SCHUNK)   // 16384

// ---------------------------------------------------------------------------
// Kernel 1: build per-pixel 20-bit target word.
// tbits[b*NHW + p] bit t = tgt_masks[b, t, 2h, 2w] > 0.5  (nearest downsample)
// ---------------------------------------------------------------------------
__global__ void k_build_tbits(const float* __restrict__ tgt,
                              uint32_t* __restrict__ tbits) {
    int idx = blockIdx.x * blockDim.x + threadIdx.x;   // 0 .. NB*NHW-1
    int b = idx >> 16;
    int p = idx & (NHW - 1);
    int h = p >> 8, w = p & 255;
    const float* base = tgt + (((size_t)b * NT) * 512 + 2 * h) * 512 + 2 * w;
    uint32_t word = 0;
#pragma unroll
    for (int t = 0; t < NT; ++t) {
        float v = base[(size_t)t * 512 * 512];
        word |= (v > 0.5f ? 1u : 0u) << t;
    }
    tbits[idx] = word;
}

// ---------------------------------------------------------------------------
// Kernel 2: Stm[b,t] = number of set pixels per target (float)
// ---------------------------------------------------------------------------
__global__ void k_stm(const uint32_t* __restrict__ tbits, float* __restrict__ Stm) {
    __shared__ int cnt[NT];
    int b = blockIdx.x;
    if (threadIdx.x < NT) cnt[threadIdx.x] = 0;
    __syncthreads();
    int local[NT];
#pragma unroll
    for (int t = 0; t < NT; ++t) local[t] = 0;
    for (int i = threadIdx.x; i < NHW; i += blockDim.x) {
        uint32_t w = tbits[b * NHW + i];
#pragma unroll
        for (int t = 0; t < NT; ++t) local[t] += (w >> t) & 1;
    }
#pragma unroll
    for (int t = 0; t < NT; ++t) atomicAdd(&cnt[t], local[t]);
    __syncthreads();
    if (threadIdx.x < NT) Stm[b * NT + threadIdx.x] = (float)cnt[threadIdx.x];
}

// ---------------------------------------------------------------------------
// Kernel 3: main reductions. One block per (b, q, chunk).
// Produces per-chunk partials:
//   A[q,t]  = sum_{p: tm=1} pm          (for cost_mask: (Sneg - A)/HW)
//   D[q,t]  = sum_{p: tm=1} sigmoid(pm) (for dice numerator)
//   Sneg[q] = sum_p softplus(pm),  Ssig[q] = sum_p sigmoid(pm)
// ---------------------------------------------------------------------------
__global__ void __launch_bounds__(256)
k_main(const float* __restrict__ pm, const uint32_t* __restrict__ tbits,
       float* __restrict__ A_part, float* __restrict__ D_part,
       float* __restrict__ SS_part) {
    int gid = blockIdx.x;
    int chunk = gid % SCHUNK;
    int q = (gid / SCHUNK) % NQ;
    int b = gid / (SCHUNK * NQ);
    int tid = threadIdx.x;

    const float4* pm4 =
        reinterpret_cast<const float4*>(pm + ((size_t)(b * NQ + q)) * NHW + chunk * CHUNK_PX);
    const uint4* tb4 =
        reinterpret_cast<const uint4*>(tbits + (size_t)b * NHW + chunk * CHUNK_PX);

    float A[NT], D[NT];
#pragma unroll
    for (int t = 0; t < NT; ++t) { A[t] = 0.0f; D[t] = 0.0f; }
    float sneg = 0.0f, ssig = 0.0f;

    const int iters = CHUNK_PX / 4 / 256;   // 16
#pragma unroll 4
    for (int it = 0; it < iters; ++it) {
        int v = it * 256 + tid;
        float4 x4 = pm4[v];
        uint4 m4 = tb4[v];
        float xs[4] = {x4.x, x4.y, x4.z, x4.w};
        uint32_t ms[4] = {m4.x, m4.y, m4.z, m4.w};
#pragma unroll
        for (int e = 0; e < 4; ++e) {
            float x = xs[e];
            uint32_t m = ms[e];
            float e1 = __expf(-fabsf(x));            // exp(-|x|) in (0,1]
            float inv = 1.0f / (1.0f + e1);
            float sig = (x >= 0.0f) ? inv : e1 * inv;
            float sp = fmaxf(x, 0.0f) + __logf(1.0f + e1);  // softplus(x)
            sneg += sp;
            ssig += sig;
#pragma unroll
            for (int t = 0; t < NT; ++t) {
                float bt = (m & (1u << t)) ? 1.0f : 0.0f;
                A[t] = fmaf(bt, x, A[t]);
                D[t] = fmaf(bt, sig, D[t]);
            }
        }
    }

    // block reduction: 42 values (A[0..19], D[0..19], sneg, ssig)
    __shared__ float red[42 * 4];
    int lane = tid & 63, wv = tid >> 6;
#pragma unroll
    for (int t = 0; t < NT; ++t) {
        float v = A[t];
        for (int o = 32; o; o >>= 1) v += __shfl_down(v, o);
        if (lane == 0) red[t * 4 + wv] = v;
    }
#pragma unroll
    for (int t = 0; t < NT; ++t) {
        float v = D[t];
        for (int o = 32; o; o >>= 1) v += __shfl_down(v, o);
        if (lane == 0) red[(NT + t) * 4 + wv] = v;
    }
    {
        float v = sneg;
        for (int o = 32; o; o >>= 1) v += __shfl_down(v, o);
        if (lane == 0) red[40 * 4 + wv] = v;
        v = ssig;
        for (int o = 32; o; o >>= 1) v += __shfl_down(v, o);
        if (lane == 0) red[41 * 4 + wv] = v;
    }
    __syncthreads();
    if (tid < 42) {
        float s = red[tid * 4] + red[tid * 4 + 1] + red[tid * 4 + 2] + red[tid * 4 + 3];
        size_t base = (size_t)((chunk * NB + b) * NQ + q);
        if (tid < NT)       A_part[base * NT + tid] = s;
        else if (tid < 40)  D_part[base * NT + (tid - NT)] = s;
        else                SS_part[base * 2 + (tid - 40)] = s;
    }
}

// ---------------------------------------------------------------------------
// Kernel 4: assemble C[b,q,t]. One block (64 threads) per (b,q).
// ---------------------------------------------------------------------------
__global__ void __launch_bounds__(64)
k_assemble(const float* __restrict__ logits, const int* __restrict__ labels,
           const float* __restrict__ A_part, const float* __restrict__ D_part,
           const float* __restrict__ SS_part, const float* __restrict__ Stm,
           float* __restrict__ Cout) {
    int bq = blockIdx.x;
    int q = bq % NQ, b = bq / NQ;
    int lane = threadIdx.x;
    const float* lg = logits + (size_t)bq * NCLS;

    float x0 = (lane < NCLS) ? lg[lane] : -INFINITY;
    float x1 = (lane + 64 < NCLS) ? lg[lane + 64] : -INFINITY;
    float mx = fmaxf(x0, x1);
    for (int o = 32; o; o >>= 1) mx = fmaxf(mx, __shfl_xor(mx, o));
    float s0 = (lane < NCLS) ? __expf(x0 - mx) : 0.0f;
    float s1 = (lane + 64 < NCLS) ? __expf(x1 - mx) : 0.0f;
    float sum = s0 + s1;
    for (int o = 32; o; o >>= 1) sum += __shfl_xor(sum, o);

    float Sneg = 0.0f, Ssig = 0.0f;
#pragma unroll
    for (int s = 0; s < SCHUNK; ++s) {
        size_t base = ((size_t)((s * NB + b) * NQ + q)) * 2;
        Sneg += SS_part[base];
        Ssig += SS_part[base + 1];
    }

    if (lane < NT) {
        float Av = 0.0f, Dv = 0.0f;
#pragma unroll
        for (int s = 0; s < SCHUNK; ++s) {
            size_t base = ((size_t)((s * NB + b) * NQ + q)) * NT + lane;
            Av += A_part[base];
            Dv += D_part[base];
        }
        int label = labels[b * NT + lane];
        float prob = __expf(lg[label] - mx) / sum;
        float cm = (Sneg - Av) * (1.0f / (float)NHW);
        float stm = Stm[b * NT + lane];
        float cd = 1.0f - (2.0f * Dv + 1.0f) / (Ssig + stm + 1.0f);
        float c = 2.0f * (-prob) + 5.0f * cm + 5.0f * cd;
        if (isnan(c)) c = 0.0f;
        Cout[(size_t)bq * NT + lane] = c;
    }
}

// ---------------------------------------------------------------------------
// Kernel 5: linear sum assignment (scipy shortest augmenting path, float64),
// on C[b].T (rows = targets 20, cols = queries 100). One wave per batch.
// ---------------------------------------------------------------------------
__global__ void __launch_bounds__(64)
k_lsa(const float* __restrict__ Cmat, float* __restrict__ out) {
    int b = blockIdx.x;
    int lane = threadIdx.x;
    __shared__ double cost[NT][NQ];
    __shared__ double u[NT], v[NQ], shortest[NQ];
    __shared__ int path[NQ], row4col[NQ], col4row[NT];
    __shared__ unsigned char SR[NT], SC[NQ];
    __shared__ int s_i, s_sink;
    __shared__ double s_minVal;
    __shared__ int qv[NT];

    for (int idx = lane; idx < NT * NQ; idx += 64) {
        int r = idx / NQ, j = idx % NQ;
        cost[r][j] = (double)Cmat[((size_t)b * NQ + j) * NT + r];
    }
    for (int j = lane; j < NQ; j += 64) { v[j] = 0.0; row4col[j] = -1; }
    if (lane < NT) { u[lane] = 0.0; col4row[lane] = -1; }
    __syncthreads();

    for (int cur = 0; cur < NT; ++cur) {
        for (int j = lane; j < NQ; j += 64) { shortest[j] = INFINITY; path[j] = -1; SC[j] = 0; }
        if (lane < NT) SR[lane] = 0;
        if (lane == 0) { s_i = cur; s_minVal = 0.0; s_sink = -1; }
        __syncthreads();

        while (true) {
            int i = s_i;
            double minVal = s_minVal;
            if (lane == 0) SR[i] = 1;
            double ui = u[i];
            double bestv = INFINITY;
            int bestj = NQ;
            for (int j = lane; j < NQ; j += 64) {
                if (!SC[j]) {
                    // same op order as reference: ((minVal + cost) - u) - v
                    double d = minVal + cost[i][j] - ui - v[j];
                    if (d < shortest[j]) { shortest[j] = d; path[j] = i; }
                    double sj = shortest[j];
                    if (sj < bestv || (sj == bestv && j < bestj)) { bestv = sj; bestj = j; }
                }
            }
            // wave argmin, tie -> lowest column index (numpy argmin semantics)
            for (int o = 32; o; o >>= 1) {
                double ov = __shfl_xor(bestv, o);
                int oj = __shfl_xor(bestj, o);
                if (ov < bestv || (ov == bestv && oj < bestj)) { bestv = ov; bestj = oj; }
            }
            __syncthreads();
            if (lane == 0) {
                SC[bestj] = 1;
                s_minVal = bestv;
                if (row4col[bestj] == -1) s_sink = bestj;
                else s_i = row4col[bestj];
            }
            __syncthreads();
            if (s_sink >= 0) break;
        }

        double minVal = s_minVal;
        int sink = s_sink;
        if (lane < NT) {
            if (lane == cur) u[lane] += minVal;
            else if (SR[lane]) u[lane] += minVal - shortest[col4row[lane]];
        }
        for (int j = lane; j < NQ; j += 64) {
            if (SC[j]) v[j] -= minVal - shortest[j];
        }
        __syncthreads();
        if (lane == 0) {
            int j = sink;
            while (true) {
                int i = path[j];
                row4col[j] = i;
                int nj = col4row[i];
                col4row[i] = j;
                j = nj;
                if (i == cur) break;
            }
        }
        __syncthreads();
    }

    if (lane < NT) qv[lane] = col4row[lane];
    __syncthreads();
    if (lane < NT) {
        int my = qv[lane];
        int rank = 0;
#pragma unroll
        for (int t2 = 0; t2 < NT; ++t2) rank += (qv[t2] < my) ? 1 : 0;
        // outputs concatenated: C (NB*NQ*NT), pred_idx (NB*NT), tgt_idx (NB*NT)
        out[NB * NQ * NT + b * NT + rank] = (float)my;          // pred_idx
        out[NB * NQ * NT + NB * NT + b * NT + rank] = (float)lane;  // tgt_idx
    }
}

// ---------------------------------------------------------------------------
extern "C" void kernel_launch(void* const* d_in, const int* in_sizes, int n_in,
                              void* d_out, int out_size, void* d_ws, size_t ws_size,
                              hipStream_t stream) {
    const float* pred_logits = (const float*)d_in[0];   // [4,100,81]
    const float* pred_masks  = (const float*)d_in[1];   // [4,100,256,256]
    const float* tgt_masks   = (const float*)d_in[2];   // [4,20,512,512]
    const int*   tgt_labels  = (const int*)d_in[3];     // [4,20]
    float* out = (float*)d_out;

    char* ws = (char*)d_ws;
    uint32_t* tbits = (uint32_t*)ws;                                  // NB*NHW u32 = 1 MB
    float* A_part  = (float*)(ws + (size_t)NB * NHW * 4);             // SCHUNK*NB*NQ*NT
    float* D_part  = A_part + (size_t)SCHUNK * NB * NQ * NT;
    float* SS_part = D_part + (size_t)SCHUNK * NB * NQ * NT;          // SCHUNK*NB*NQ*2
    float* Stm     = SS_part + (size_t)SCHUNK * NB * NQ * 2;          // NB*NT

    k_build_tbits<<<NB * NHW / 256, 256, 0, stream>>>(tgt_masks, tbits);
    k_stm<<<NB, 256, 0, stream>>>(tbits, Stm);
    k_main<<<NB * NQ * SCHUNK, 256, 0, stream>>>(pred_masks, tbits, A_part, D_part, SS_part);
    k_assemble<<<NB * NQ, 64, 0, stream>>>(pred_logits, tgt_labels, A_part, D_part,
                                           SS_part, Stm, out);
    k_lsa<<<NB, 64, 0, stream>>>(out, out);
}

// Round 2
// 167.641 us; speedup vs baseline: 1.6984x; 1.6984x over previous
//
#include <hip/hip_runtime.h>
#include <hip/hip_bf16.h>
#include <math.h>
#include <stdint.h>

#define NB 4
#define NQ 100
#define NCLS 81
#define NT 20
#define NH 256
#define NW 256
#define NHW 65536
#define SCHUNK 4
#define CHUNK_PX (NHW / SCHUNK)   // 16384

// ---------------------------------------------------------------------------
// Kernel 0: zero the Stm integer accumulator (ws is poisoned, not re-poisoned)
// ---------------------------------------------------------------------------
__global__ void k_init(int* __restrict__ StmI) {
    if (threadIdx.x < NB * NT) StmI[threadIdx.x] = 0;
}

// ---------------------------------------------------------------------------
// Kernel 1: build per-pixel 20-bit target word AND accumulate per-target
// popcounts (Stm) via ballot + popcount + int atomics (deterministic).
// tbits[b*NHW + p] bit t = tgt_masks[b, t, 2h, 2w] > 0.5  (nearest downsample)
// ---------------------------------------------------------------------------
__global__ void __launch_bounds__(256)
k_build_tbits(const float* __restrict__ tgt, uint32_t* __restrict__ tbits,
              int* __restrict__ StmI) {
    int idx = blockIdx.x * blockDim.x + threadIdx.x;   // 0 .. NB*NHW-1
    int b = idx >> 16;
    int p = idx & (NHW - 1);
    int h = p >> 8, w = p & 255;
    const float* base = tgt + (((size_t)b * NT) * 512 + 2 * h) * 512 + 2 * w;
    uint32_t word = 0;
#pragma unroll
    for (int t = 0; t < NT; ++t) {
        float v = base[(size_t)t * 512 * 512];
        word |= (v > 0.5f ? 1u : 0u) << t;
    }
    tbits[idx] = word;

    // per-block popcount of each bit, then one global atomic per (block, t)
    __shared__ int cnt[NT];
    if (threadIdx.x < NT) cnt[threadIdx.x] = 0;
    __syncthreads();
    int lane = threadIdx.x & 63;
#pragma unroll
    for (int t = 0; t < NT; ++t) {
        unsigned long long m = __ballot((word >> t) & 1u);
        if (lane == 0) atomicAdd(&cnt[t], (int)__popcll(m));
    }
    __syncthreads();
    if (threadIdx.x < NT) atomicAdd(&StmI[b * NT + threadIdx.x], cnt[threadIdx.x]);
}

// ---------------------------------------------------------------------------
// Kernel 3: main reductions. One block per (b, q, chunk).
// Produces per-chunk partials:
//   A[q,t]  = sum_{p: tm=1} pm          (for cost_mask: (Sneg - A)/HW)
//   D[q,t]  = sum_{p: tm=1} sigmoid(pm) (for dice numerator)
//   Sneg[q] = sum_p softplus(pm),  Ssig[q] = sum_p sigmoid(pm)
// ---------------------------------------------------------------------------
__global__ void __launch_bounds__(256)
k_main(const float* __restrict__ pm, const uint32_t* __restrict__ tbits,
       float* __restrict__ A_part, float* __restrict__ D_part,
       float* __restrict__ SS_part) {
    int gid = blockIdx.x;
    int chunk = gid % SCHUNK;
    int q = (gid / SCHUNK) % NQ;
    int b = gid / (SCHUNK * NQ);
    int tid = threadIdx.x;

    const float4* pm4 =
        reinterpret_cast<const float4*>(pm + ((size_t)(b * NQ + q)) * NHW + chunk * CHUNK_PX);
    const uint4* tb4 =
        reinterpret_cast<const uint4*>(tbits + (size_t)b * NHW + chunk * CHUNK_PX);

    float A[NT], D[NT];
#pragma unroll
    for (int t = 0; t < NT; ++t) { A[t] = 0.0f; D[t] = 0.0f; }
    float sneg = 0.0f, ssig = 0.0f;

    const int iters = CHUNK_PX / 4 / 256;   // 16
#pragma unroll 4
    for (int it = 0; it < iters; ++it) {
        int v = it * 256 + tid;
        float4 x4 = pm4[v];
        uint4 m4 = tb4[v];
        float xs[4] = {x4.x, x4.y, x4.z, x4.w};
        uint32_t ms[4] = {m4.x, m4.y, m4.z, m4.w};
#pragma unroll
        for (int e = 0; e < 4; ++e) {
            float x = xs[e];
            uint32_t m = ms[e];
            float e1 = __expf(-fabsf(x));            // exp(-|x|) in (0,1]
            float inv = 1.0f / (1.0f + e1);
            float sig = (x >= 0.0f) ? inv : e1 * inv;
            float sp = fmaxf(x, 0.0f) + __logf(1.0f + e1);  // softplus(x)
            sneg += sp;
            ssig += sig;
#pragma unroll
            for (int t = 0; t < NT; ++t) {
                float bt = (m & (1u << t)) ? 1.0f : 0.0f;
                A[t] = fmaf(bt, x, A[t]);
                D[t] = fmaf(bt, sig, D[t]);
            }
        }
    }

    // block reduction: 42 values (A[0..19], D[0..19], sneg, ssig)
    __shared__ float red[42 * 4];
    int lane = tid & 63, wv = tid >> 6;
#pragma unroll
    for (int t = 0; t < NT; ++t) {
        float v = A[t];
        for (int o = 32; o; o >>= 1) v += __shfl_down(v, o);
        if (lane == 0) red[t * 4 + wv] = v;
    }
#pragma unroll
    for (int t = 0; t < NT; ++t) {
        float v = D[t];
        for (int o = 32; o; o >>= 1) v += __shfl_down(v, o);
        if (lane == 0) red[(NT + t) * 4 + wv] = v;
    }
    {
        float v = sneg;
        for (int o = 32; o; o >>= 1) v += __shfl_down(v, o);
        if (lane == 0) red[40 * 4 + wv] = v;
        v = ssig;
        for (int o = 32; o; o >>= 1) v += __shfl_down(v, o);
        if (lane == 0) red[41 * 4 + wv] = v;
    }
    __syncthreads();
    if (tid < 42) {
        float s = red[tid * 4] + red[tid * 4 + 1] + red[tid * 4 + 2] + red[tid * 4 + 3];
        size_t base = (size_t)((chunk * NB + b) * NQ + q);
        if (tid < NT)       A_part[base * NT + tid] = s;
        else if (tid < 40)  D_part[base * NT + (tid - NT)] = s;
        else                SS_part[base * 2 + (tid - 40)] = s;
    }
}

// ---------------------------------------------------------------------------
// Kernel 4: assemble C[b,q,t]. One block (64 threads) per (b,q).
// ---------------------------------------------------------------------------
__global__ void __launch_bounds__(64)
k_assemble(const float* __restrict__ logits, const int* __restrict__ labels,
           const float* __restrict__ A_part, const float* __restrict__ D_part,
           const float* __restrict__ SS_part, const int* __restrict__ StmI,
           float* __restrict__ Cout) {
    int bq = blockIdx.x;
    int q = bq % NQ, b = bq / NQ;
    int lane = threadIdx.x;
    const float* lg = logits + (size_t)bq * NCLS;

    float x0 = (lane < NCLS) ? lg[lane] : -INFINITY;
    float x1 = (lane + 64 < NCLS) ? lg[lane + 64] : -INFINITY;
    float mx = fmaxf(x0, x1);
    for (int o = 32; o; o >>= 1) mx = fmaxf(mx, __shfl_xor(mx, o));
    float s0 = (lane < NCLS) ? __expf(x0 - mx) : 0.0f;
    float s1 = (lane + 64 < NCLS) ? __expf(x1 - mx) : 0.0f;
    float sum = s0 + s1;
    for (int o = 32; o; o >>= 1) sum += __shfl_xor(sum, o);

    float Sneg = 0.0f, Ssig = 0.0f;
#pragma unroll
    for (int s = 0; s < SCHUNK; ++s) {
        size_t base = ((size_t)((s * NB + b) * NQ + q)) * 2;
        Sneg += SS_part[base];
        Ssig += SS_part[base + 1];
    }

    if (lane < NT) {
        float Av = 0.0f, Dv = 0.0f;
#pragma unroll
        for (int s = 0; s < SCHUNK; ++s) {
            size_t base = ((size_t)((s * NB + b) * NQ + q)) * NT + lane;
            Av += A_part[base];
            Dv += D_part[base];
        }
        int label = labels[b * NT + lane];
        float prob = __expf(lg[label] - mx) / sum;
        float cm = (Sneg - Av) * (1.0f / (float)NHW);
        float stm = (float)StmI[b * NT + lane];
        float cd = 1.0f - (2.0f * Dv + 1.0f) / (Ssig + stm + 1.0f);
        float c = 2.0f * (-prob) + 5.0f * cm + 5.0f * cd;
        if (isnan(c)) c = 0.0f;
        Cout[(size_t)bq * NT + lane] = c;
    }
}

// ---------------------------------------------------------------------------
// Kernel 5: linear sum assignment (scipy shortest augmenting path, float64),
// on C[b].T (rows = targets 20, cols = queries 100). One wave per batch.
// ---------------------------------------------------------------------------
__global__ void __launch_bounds__(64)
k_lsa(const float* __restrict__ Cmat, float* __restrict__ out) {
    int b = blockIdx.x;
    int lane = threadIdx.x;
    __shared__ double cost[NT][NQ];
    __shared__ double u[NT], v[NQ], shortest[NQ];
    __shared__ int path[NQ], row4col[NQ], col4row[NT];
    __shared__ unsigned char SR[NT], SC[NQ];
    __shared__ int s_i, s_sink;
    __shared__ double s_minVal;
    __shared__ int qv[NT];

    for (int idx = lane; idx < NT * NQ; idx += 64) {
        int r = idx / NQ, j = idx % NQ;
        cost[r][j] = (double)Cmat[((size_t)b * NQ + j) * NT + r];
    }
    for (int j = lane; j < NQ; j += 64) { v[j] = 0.0; row4col[j] = -1; }
    if (lane < NT) { u[lane] = 0.0; col4row[lane] = -1; }
    __syncthreads();

    for (int cur = 0; cur < NT; ++cur) {
        for (int j = lane; j < NQ; j += 64) { shortest[j] = INFINITY; path[j] = -1; SC[j] = 0; }
        if (lane < NT) SR[lane] = 0;
        if (lane == 0) { s_i = cur; s_minVal = 0.0; s_sink = -1; }
        __syncthreads();

        while (true) {
            int i = s_i;
            double minVal = s_minVal;
            if (lane == 0) SR[i] = 1;
            double ui = u[i];
            double bestv = INFINITY;
            int bestj = NQ;
            for (int j = lane; j < NQ; j += 64) {
                if (!SC[j]) {
                    // same op order as reference: ((minVal + cost) - u) - v
                    double d = minVal + cost[i][j] - ui - v[j];
                    if (d < shortest[j]) { shortest[j] = d; path[j] = i; }
                    double sj = shortest[j];
                    if (sj < bestv || (sj == bestv && j < bestj)) { bestv = sj; bestj = j; }
                }
            }
            // wave argmin, tie -> lowest column index (numpy argmin semantics)
            for (int o = 32; o; o >>= 1) {
                double ov = __shfl_xor(bestv, o);
                int oj = __shfl_xor(bestj, o);
                if (ov < bestv || (ov == bestv && oj < bestj)) { bestv = ov; bestj = oj; }
            }
            __syncthreads();
            if (lane == 0) {
                SC[bestj] = 1;
                s_minVal = bestv;
                if (row4col[bestj] == -1) s_sink = bestj;
                else s_i = row4col[bestj];
            }
            __syncthreads();
            if (s_sink >= 0) break;
        }

        double minVal = s_minVal;
        int sink = s_sink;
        if (lane < NT) {
            if (lane == cur) u[lane] += minVal;
            else if (SR[lane]) u[lane] += minVal - shortest[col4row[lane]];
        }
        for (int j = lane; j < NQ; j += 64) {
            if (SC[j]) v[j] -= minVal - shortest[j];
        }
        __syncthreads();
        if (lane == 0) {
            int j = sink;
            while (true) {
                int i = path[j];
                row4col[j] = i;
                int nj = col4row[i];
                col4row[i] = j;
                j = nj;
                if (i == cur) break;
            }
        }
        __syncthreads();
    }

    if (lane < NT) qv[lane] = col4row[lane];
    __syncthreads();
    if (lane < NT) {
        int my = qv[lane];
        int rank = 0;
#pragma unroll
        for (int t2 = 0; t2 < NT; ++t2) rank += (qv[t2] < my) ? 1 : 0;
        // outputs concatenated: C (NB*NQ*NT), pred_idx (NB*NT), tgt_idx (NB*NT)
        out[NB * NQ * NT + b * NT + rank] = (float)my;          // pred_idx
        out[NB * NQ * NT + NB * NT + b * NT + rank] = (float)lane;  // tgt_idx
    }
}

// ---------------------------------------------------------------------------
extern "C" void kernel_launch(void* const* d_in, const int* in_sizes, int n_in,
                              void* d_out, int out_size, void* d_ws, size_t ws_size,
                              hipStream_t stream) {
    const float* pred_logits = (const float*)d_in[0];   // [4,100,81]
    const float* pred_masks  = (const float*)d_in[1];   // [4,100,256,256]
    const float* tgt_masks   = (const float*)d_in[2];   // [4,20,512,512]
    const int*   tgt_labels  = (const int*)d_in[3];     // [4,20]
    float* out = (float*)d_out;

    char* ws = (char*)d_ws;
    uint32_t* tbits = (uint32_t*)ws;                                  // NB*NHW u32 = 1 MB
    float* A_part  = (float*)(ws + (size_t)NB * NHW * 4);             // SCHUNK*NB*NQ*NT
    float* D_part  = A_part + (size_t)SCHUNK * NB * NQ * NT;
    float* SS_part = D_part + (size_t)SCHUNK * NB * NQ * NT;          // SCHUNK*NB*NQ*2
    int*   StmI    = (int*)(SS_part + (size_t)SCHUNK * NB * NQ * 2);  // NB*NT ints

    k_init<<<1, 128, 0, stream>>>(StmI);
    k_build_tbits<<<NB * NHW / 256, 256, 0, stream>>>(tgt_masks, tbits, StmI);
    k_main<<<NB * NQ * SCHUNK, 256, 0, stream>>>(pred_masks, tbits, A_part, D_part, SS_part);
    k_assemble<<<NB * NQ, 64, 0, stream>>>(pred_logits, tgt_labels, A_part, D_part,
                                           SS_part, StmI, out);
    k_lsa<<<NB, 64, 0, stream>>>(out, out);
}

// Round 3
// 151.964 us; speedup vs baseline: 1.8736x; 1.1032x over previous
//
#include <hip/hip_runtime.h>
#include <hip/hip_bf16.h>
#include <math.h>
#include <stdint.h>

#define NB 4
#define NQ 100
#define NCLS 81
#define NT 20
#define NHW 65536

#define SC2 128                  // split-K chunks for k_main
#define CPX2 (NHW / SC2)         // 512 pixels per block
#define KSTEPS (CPX2 / 16)       // 32 MFMA K-steps (16 px each)

typedef __attribute__((ext_vector_type(8))) short bf16x8;
typedef __attribute__((ext_vector_type(16))) float f32x16;

// RNE fp32 -> bf16 (compiler typically fuses pairs into v_cvt_pk_bf16_f32)
__device__ inline short bf16c(float f) {
    uint32_t u = __builtin_bit_cast(uint32_t, f);
    return (short)((u + 0x7FFFu + ((u >> 16) & 1u)) >> 16);
}

// ---------------------------------------------------------------------------
// Kernel 0: zero the Stm integer accumulator (ws is poisoned, not re-poisoned)
// ---------------------------------------------------------------------------
__global__ void k_init(int* __restrict__ StmI) {
    if (threadIdx.x < NB * NT) StmI[threadIdx.x] = 0;
}

// ---------------------------------------------------------------------------
// Kernel 1: per-pixel 20-bit target word + per-target popcounts (Stm).
// tbits[b*NHW + p] bit t = tgt_masks[b, t, 2h, 2w] > 0.5  (nearest downsample)
// ---------------------------------------------------------------------------
__global__ void __launch_bounds__(256)
k_build_tbits(const float* __restrict__ tgt, uint32_t* __restrict__ tbits,
              int* __restrict__ StmI) {
    int idx = blockIdx.x * blockDim.x + threadIdx.x;   // 0 .. NB*NHW-1
    int b = idx >> 16;
    int p = idx & (NHW - 1);
    int h = p >> 8, w = p & 255;
    const float* base = tgt + (((size_t)b * NT) * 512 + 2 * h) * 512 + 2 * w;
    uint32_t word = 0;
#pragma unroll
    for (int t = 0; t < NT; ++t) {
        float v = base[(size_t)t * 512 * 512];
        word |= (v > 0.5f ? 1u : 0u) << t;
    }
    tbits[idx] = word;

    __shared__ int cnt[NT];
    if (threadIdx.x < NT) cnt[threadIdx.x] = 0;
    __syncthreads();
    int lane = threadIdx.x & 63;
#pragma unroll
    for (int t = 0; t < NT; ++t) {
        unsigned long long m = __ballot((word >> t) & 1u);
        if (lane == 0) atomicAdd(&cnt[t], (int)__popcll(m));
    }
    __syncthreads();
    if (threadIdx.x < NT) atomicAdd(&StmI[b * NT + threadIdx.x], cnt[threadIdx.x]);
}

// ---------------------------------------------------------------------------
// Kernel 2: MFMA main pass. One block per (b, K-chunk of 512 px).
// 4 waves; wave w owns queries 32w..32w+31 (rows >= 100 are padded/ignored).
// Two GEMM accumulators per wave (x-GEMM -> A, sig-GEMM -> D) over a 32-target
// N-tile; column 20 of B is all-ones so D[:,20] = sum(sigmoid) for free.
// Also accumulates per-q softplus row-sums lane-locally.
// ---------------------------------------------------------------------------
__global__ void __launch_bounds__(256)
k_main(const float* __restrict__ pm, const uint32_t* __restrict__ tbits,
       float* __restrict__ A_part, float* __restrict__ D_part,
       float* __restrict__ Sp_part) {
    int gid = blockIdx.x;
    int chunk = gid & (SC2 - 1);
    int b = gid >> 7;                 // SC2 == 128
    int tid = threadIdx.x;
    int wv = tid >> 6, lane = tid & 63;
    int p0 = chunk * CPX2;

    __shared__ uint32_t s_tb[CPX2];          // 2 KB
    __shared__ short s_bf[KSTEPS][512];      // 32 KB of B-fragments (bf16)

    for (int i = tid; i < CPX2; i += 256) s_tb[i] = tbits[b * NHW + p0 + i];
    __syncthreads();

    // Build B-frags: B[k][col] for K-step ls; lane l holds col=l&31,
    // k = (l>>5)*8 + e  (same k-mapping used for the A operand below).
    for (int c = tid; c < KSTEPS * 64; c += 256) {
        int ls = c >> 6, l = c & 63;
        int col = l & 31;
        int kbase = ls * 16 + ((l >> 5) << 3);
        uint32_t pk[4];
#pragma unroll
        for (int e2 = 0; e2 < 4; ++e2) {
            uint32_t w0 = s_tb[kbase + 2 * e2];
            uint32_t w1 = s_tb[kbase + 2 * e2 + 1];
            uint32_t lo, hi;
            if (col < NT)       { lo = ((w0 >> col) & 1u) ? 0x3F80u : 0u;
                                  hi = ((w1 >> col) & 1u) ? 0x3F80u : 0u; }
            else if (col == NT) { lo = 0x3F80u; hi = 0x3F80u; }   // ones col
            else                { lo = 0u; hi = 0u; }
            pk[e2] = lo | (hi << 16);
        }
        *reinterpret_cast<uint4*>(&s_bf[ls][l * 8]) = *reinterpret_cast<const uint4*>(pk);
    }
    __syncthreads();

    int row = lane & 31;
    int q = wv * 32 + row;
    int qc = (q < NQ) ? q : 0;        // clamp: padded rows read row 0 (discarded)
    const float4* xp = reinterpret_cast<const float4*>(
        pm + ((size_t)(b * NQ + qc)) * NHW + p0 + ((lane >> 5) << 3));

    f32x16 accA, accD;
#pragma unroll
    for (int r = 0; r < 16; ++r) { accA[r] = 0.0f; accD[r] = 0.0f; }
    float spsum = 0.0f;

#pragma unroll 2
    for (int s = 0; s < KSTEPS; ++s) {
        float4 xa = xp[s * 4];
        float4 xb4 = xp[s * 4 + 1];
        float xs[8] = {xa.x, xa.y, xa.z, xa.w, xb4.x, xb4.y, xb4.z, xb4.w};
        bf16x8 af, sf;
#pragma unroll
        for (int e = 0; e < 8; ++e) {
            float xi = xs[e];
            float e1 = __expf(-fabsf(xi));          // exp(-|x|)
            float tt = 1.0f + e1;
            float inv = __builtin_amdgcn_rcpf(tt);
            float sig = (xi >= 0.0f) ? inv : e1 * inv;
            spsum += fmaxf(xi, 0.0f) + __logf(tt);  // softplus(x)
            af[e] = bf16c(xi);
            sf[e] = bf16c(sig);
        }
        bf16x8 bf = *reinterpret_cast<const bf16x8*>(&s_bf[s][lane * 8]);
        accA = __builtin_amdgcn_mfma_f32_32x32x16_bf16(af, bf, accA, 0, 0, 0);
        accD = __builtin_amdgcn_mfma_f32_32x32x16_bf16(sf, bf, accD, 0, 0, 0);
    }

    // Epilogue: C/D layout (verified): col = lane&31, row = (r&3)+8*(r>>2)+4*(lane>>5)
    int t = lane & 31;
#pragma unroll
    for (int r = 0; r < 16; ++r) {
        int rowD = (r & 3) + 8 * (r >> 2) + 4 * (lane >> 5);
        int qo = wv * 32 + rowD;
        if (qo < NQ && t <= NT) {
            size_t base = ((size_t)(chunk * NB + b) * NQ + qo) * (NT + 1) + t;
            A_part[base] = accA[r];
            D_part[base] = accD[r];
        }
    }
    // softplus row-sum: lanes l and l+32 hold halves of row q
    spsum += __shfl_xor(spsum, 32);
    if (lane < 32 && q < NQ)
        Sp_part[(size_t)(chunk * NB + b) * NQ + q] = spsum;
}

// ---------------------------------------------------------------------------
// Kernel 3: assemble C[b,q,t]. One block (64 threads) per (b,q).
// ---------------------------------------------------------------------------
__global__ void __launch_bounds__(64)
k_assemble(const float* __restrict__ logits, const int* __restrict__ labels,
           const float* __restrict__ A_part, const float* __restrict__ D_part,
           const float* __restrict__ Sp_part, const int* __restrict__ StmI,
           float* __restrict__ Cout) {
    int bq = blockIdx.x;
    int q = bq % NQ, b = bq / NQ;
    int lane = threadIdx.x;
    const float* lg = logits + (size_t)bq * NCLS;

    float x0 = (lane < NCLS) ? lg[lane] : -INFINITY;
    float x1 = (lane + 64 < NCLS) ? lg[lane + 64] : -INFINITY;
    float mx = fmaxf(x0, x1);
    for (int o = 32; o; o >>= 1) mx = fmaxf(mx, __shfl_xor(mx, o));
    float s0 = (lane < NCLS) ? __expf(x0 - mx) : 0.0f;
    float s1 = (lane + 64 < NCLS) ? __expf(x1 - mx) : 0.0f;
    float sum = s0 + s1;
    for (int o = 32; o; o >>= 1) sum += __shfl_xor(sum, o);

    float At = 0.0f, Dt = 0.0f, Sneg = 0.0f;
    int t = lane;
    for (int c = 0; c < SC2; ++c) {
        size_t base = (size_t)(c * NB + b) * NQ + q;
        Sneg += Sp_part[base];                       // broadcast load
        if (t <= NT) {
            At += A_part[base * (NT + 1) + t];
            Dt += D_part[base * (NT + 1) + t];
        }
    }
    float Ssig = __shfl(Dt, NT);                     // ones-column of D-GEMM

    if (t < NT) {
        int label = labels[b * NT + t];
        float prob = __expf(lg[label] - mx) / sum;
        float cm = (Sneg - At) * (1.0f / (float)NHW);
        float stm = (float)StmI[b * NT + t];
        float cd = 1.0f - (2.0f * Dt + 1.0f) / (Ssig + stm + 1.0f);
        float c = 2.0f * (-prob) + 5.0f * cm + 5.0f * cd;
        if (isnan(c)) c = 0.0f;
        Cout[(size_t)bq * NT + t] = c;
    }
}

// ---------------------------------------------------------------------------
// Kernel 4: linear sum assignment (scipy shortest augmenting path, float64),
// on C[b].T (rows = targets 20, cols = queries 100). One wave per batch.
// ---------------------------------------------------------------------------
__global__ void __launch_bounds__(64)
k_lsa(const float* __restrict__ Cmat, float* __restrict__ out) {
    int b = blockIdx.x;
    int lane = threadIdx.x;
    __shared__ double cost[NT][NQ];
    __shared__ double u[NT], v[NQ], shortest[NQ];
    __shared__ int path[NQ], row4col[NQ], col4row[NT];
    __shared__ unsigned char SR[NT], SC[NQ];
    __shared__ int s_i, s_sink;
    __shared__ double s_minVal;
    __shared__ int qv[NT];

    for (int idx = lane; idx < NT * NQ; idx += 64) {
        int r = idx / NQ, j = idx % NQ;
        cost[r][j] = (double)Cmat[((size_t)b * NQ + j) * NT + r];
    }
    for (int j = lane; j < NQ; j += 64) { v[j] = 0.0; row4col[j] = -1; }
    if (lane < NT) { u[lane] = 0.0; col4row[lane] = -1; }
    __syncthreads();

    for (int cur = 0; cur < NT; ++cur) {
        for (int j = lane; j < NQ; j += 64) { shortest[j] = INFINITY; path[j] = -1; SC[j] = 0; }
        if (lane < NT) SR[lane] = 0;
        if (lane == 0) { s_i = cur; s_minVal = 0.0; s_sink = -1; }
        __syncthreads();

        while (true) {
            int i = s_i;
            double minVal = s_minVal;
            if (lane == 0) SR[i] = 1;
            double ui = u[i];
            double bestv = INFINITY;
            int bestj = NQ;
            for (int j = lane; j < NQ; j += 64) {
                if (!SC[j]) {
                    double d = minVal + cost[i][j] - ui - v[j];
                    if (d < shortest[j]) { shortest[j] = d; path[j] = i; }
                    double sj = shortest[j];
                    if (sj < bestv || (sj == bestv && j < bestj)) { bestv = sj; bestj = j; }
                }
            }
            for (int o = 32; o; o >>= 1) {
                double ov = __shfl_xor(bestv, o);
                int oj = __shfl_xor(bestj, o);
                if (ov < bestv || (ov == bestv && oj < bestj)) { bestv = ov; bestj = oj; }
            }
            __syncthreads();
            if (lane == 0) {
                SC[bestj] = 1;
                s_minVal = bestv;
                if (row4col[bestj] == -1) s_sink = bestj;
                else s_i = row4col[bestj];
            }
            __syncthreads();
            if (s_sink >= 0) break;
        }

        double minVal = s_minVal;
        int sink = s_sink;
        if (lane < NT) {
            if (lane == cur) u[lane] += minVal;
            else if (SR[lane]) u[lane] += minVal - shortest[col4row[lane]];
        }
        for (int j = lane; j < NQ; j += 64) {
            if (SC[j]) v[j] -= minVal - shortest[j];
        }
        __syncthreads();
        if (lane == 0) {
            int j = sink;
            while (true) {
                int i = path[j];
                row4col[j] = i;
                int nj = col4row[i];
                col4row[i] = j;
                j = nj;
                if (i == cur) break;
            }
        }
        __syncthreads();
    }

    if (lane < NT) qv[lane] = col4row[lane];
    __syncthreads();
    if (lane < NT) {
        int my = qv[lane];
        int rank = 0;
#pragma unroll
        for (int t2 = 0; t2 < NT; ++t2) rank += (qv[t2] < my) ? 1 : 0;
        out[NB * NQ * NT + b * NT + rank] = (float)my;              // pred_idx
        out[NB * NQ * NT + NB * NT + b * NT + rank] = (float)lane;  // tgt_idx
    }
}

// ---------------------------------------------------------------------------
extern "C" void kernel_launch(void* const* d_in, const int* in_sizes, int n_in,
                              void* d_out, int out_size, void* d_ws, size_t ws_size,
                              hipStream_t stream) {
    const float* pred_logits = (const float*)d_in[0];   // [4,100,81]
    const float* pred_masks  = (const float*)d_in[1];   // [4,100,256,256]
    const float* tgt_masks   = (const float*)d_in[2];   // [4,20,512,512]
    const int*   tgt_labels  = (const int*)d_in[3];     // [4,20]
    float* out = (float*)d_out;

    char* ws = (char*)d_ws;
    uint32_t* tbits = (uint32_t*)ws;                                  // 1 MB
    float* A_part  = (float*)(ws + (size_t)NB * NHW * 4);             // SC2*NB*NQ*21
    float* D_part  = A_part + (size_t)SC2 * NB * NQ * (NT + 1);
    float* Sp_part = D_part + (size_t)SC2 * NB * NQ * (NT + 1);       // SC2*NB*NQ
    int*   StmI    = (int*)(Sp_part + (size_t)SC2 * NB * NQ);         // NB*NT ints

    k_init<<<1, 128, 0, stream>>>(StmI);
    k_build_tbits<<<NB * NHW / 256, 256, 0, stream>>>(tgt_masks, tbits, StmI);
    k_main<<<NB * SC2, 256, 0, stream>>>(pred_masks, tbits, A_part, D_part, Sp_part);
    k_assemble<<<NB * NQ, 64, 0, stream>>>(pred_logits, tgt_labels, A_part, D_part,
                                           Sp_part, StmI, out);
    k_lsa<<<NB, 64, 0, stream>>>(out, out);
}

// Round 5
// 122.182 us; speedup vs baseline: 2.3303x; 1.2437x over previous
//
#include <hip/hip_runtime.h>
#include <hip/hip_bf16.h>
#include <math.h>
#include <stdint.h>

#define NB 4
#define NQ 100
#define NCLS 81
#define NT 20
#define NHW 65536

#define SC2 256                  // split-K chunks: one 256-px output row each
#define CPX2 (NHW / SC2)         // 256 pixels per block
#define KSTEPS (CPX2 / 16)       // 16 MFMA K-steps (16 px each)

typedef __attribute__((ext_vector_type(8))) short bf16x8;
typedef __attribute__((ext_vector_type(16))) float f32x16;

// RNE fp32 -> bf16
__device__ inline short bf16c(float f) {
    uint32_t u = __builtin_bit_cast(uint32_t, f);
    return (short)((u + 0x7FFFu + ((u >> 16) & 1u)) >> 16);
}

// ---------------------------------------------------------------------------
// Kernel 0: zero the Stm integer accumulator (ws is poisoned, not re-poisoned)
// ---------------------------------------------------------------------------
__global__ void k_init(int* __restrict__ StmI) {
    if (threadIdx.x < NB * NT) StmI[threadIdx.x] = 0;
}

// ---------------------------------------------------------------------------
// Kernel 1: fused main pass. One block per (b, output row h).
//  phase A: threads 0..127 gather tgt[b, :, 2h, src cols 4i..4i+3] (float4);
//           v.x -> dst pixel 2i, v.z -> dst pixel 2i+1 (nearest downsample).
//           Then all 256 threads ballot-popcount s_tb[tid] for Stm.
//  phase B: build MFMA B-fragments (bf16 0/1; col 20 = all-ones -> Ssig free)
//  phase C: 4 waves x 32-q rows: sigmoid/softplus VALU + two 32x32x16 bf16
//           MFMAs per K-step (x-GEMM -> A, sig-GEMM -> D), split-K partials.
// ---------------------------------------------------------------------------
__global__ void __launch_bounds__(256)
k_main(const float* __restrict__ pm, const float* __restrict__ tgt,
       float* __restrict__ A_part, float* __restrict__ D_part,
       float* __restrict__ Sp_part, int* __restrict__ StmI) {
    int gid = blockIdx.x;
    int chunk = gid & (SC2 - 1);          // == output row h
    int b = gid >> 8;                     // SC2 == 256
    int tid = threadIdx.x;
    int wv = tid >> 6, lane = tid & 63;
    int p0 = chunk * CPX2;

    __shared__ uint32_t s_tb[CPX2];          // 1 KB (256 pixel words)
    __shared__ short s_bf[KSTEPS][512];      // 16 KB of B-fragments (bf16)
    __shared__ int cnt[NT];

    // ---- phase A: gather + tbits ----
    if (tid < 128) {
        // thread i covers dst pixels (2i, 2i+1): src cols 4i, 4i+2 of row 2h
        const float* base = tgt + (((size_t)b * NT) * 512 + 2 * chunk) * 512 + 4 * tid;
        uint32_t w0 = 0, w1 = 0;
#pragma unroll
        for (int t = 0; t < NT; ++t) {
            float4 v = *reinterpret_cast<const float4*>(base + (size_t)t * 512 * 512);
            w0 |= (v.x > 0.5f ? 1u : 0u) << t;
            w1 |= (v.z > 0.5f ? 1u : 0u) << t;
        }
        s_tb[2 * tid] = w0;
        s_tb[2 * tid + 1] = w1;
    }
    if (tid < NT) cnt[tid] = 0;
    __syncthreads();

    // ---- Stm popcount: uniform over all 256 threads, one pixel word each ----
    {
        uint32_t w = s_tb[tid];
#pragma unroll
        for (int t = 0; t < NT; ++t) {
            unsigned long long m = __ballot((w >> t) & 1u);
            if (lane == 0) atomicAdd(&cnt[t], (int)__popcll(m));
        }
    }

    // ---- phase B: build B-frags. lane l holds col=l&31, k = (l>>5)*8 + e ----
    for (int c = tid; c < KSTEPS * 64; c += 256) {
        int ls = c >> 6, l = c & 63;
        int col = l & 31;
        int kbase = ls * 16 + ((l >> 5) << 3);
        uint32_t pk[4];
#pragma unroll
        for (int e2 = 0; e2 < 4; ++e2) {
            uint32_t w0 = s_tb[kbase + 2 * e2];
            uint32_t w1 = s_tb[kbase + 2 * e2 + 1];
            uint32_t lo, hi;
            if (col < NT)       { lo = ((w0 >> col) & 1u) ? 0x3F80u : 0u;
                                  hi = ((w1 >> col) & 1u) ? 0x3F80u : 0u; }
            else if (col == NT) { lo = 0x3F80u; hi = 0x3F80u; }   // ones col
            else                { lo = 0u; hi = 0u; }
            pk[e2] = lo | (hi << 16);
        }
        *reinterpret_cast<uint4*>(&s_bf[ls][l * 8]) = *reinterpret_cast<const uint4*>(pk);
    }
    __syncthreads();
    if (tid < NT) atomicAdd(&StmI[b * NT + tid], cnt[tid]);

    // ---- phase C: K-loop ----
    int row = lane & 31;
    int q = wv * 32 + row;
    int qc = (q < NQ) ? q : 0;        // padded rows read row 0 (discarded)
    const float4* xp = reinterpret_cast<const float4*>(
        pm + ((size_t)(b * NQ + qc)) * NHW + p0 + ((lane >> 5) << 3));

    f32x16 accA, accD;
#pragma unroll
    for (int r = 0; r < 16; ++r) { accA[r] = 0.0f; accD[r] = 0.0f; }
    float spsum = 0.0f;

#pragma unroll 2
    for (int s = 0; s < KSTEPS; ++s) {
        float4 xa = xp[s * 4];
        float4 xb4 = xp[s * 4 + 1];
        float xs[8] = {xa.x, xa.y, xa.z, xa.w, xb4.x, xb4.y, xb4.z, xb4.w};
        bf16x8 af, sf;
#pragma unroll
        for (int e = 0; e < 8; ++e) {
            float xi = xs[e];
            float e1 = __expf(-fabsf(xi));          // exp(-|x|)
            float tt = 1.0f + e1;
            float inv = __builtin_amdgcn_rcpf(tt);
            float sig = (xi >= 0.0f) ? inv : e1 * inv;
            spsum += fmaxf(xi, 0.0f) + __logf(tt);  // softplus(x)
            af[e] = bf16c(xi);
            sf[e] = bf16c(sig);
        }
        bf16x8 bf = *reinterpret_cast<const bf16x8*>(&s_bf[s][lane * 8]);
        accA = __builtin_amdgcn_mfma_f32_32x32x16_bf16(af, bf, accA, 0, 0, 0);
        accD = __builtin_amdgcn_mfma_f32_32x32x16_bf16(sf, bf, accD, 0, 0, 0);
    }

    // Epilogue: C/D layout (verified): col = lane&31, row = (r&3)+8*(r>>2)+4*(lane>>5)
    int t = lane & 31;
#pragma unroll
    for (int r = 0; r < 16; ++r) {
        int rowD = (r & 3) + 8 * (r >> 2) + 4 * (lane >> 5);
        int qo = wv * 32 + rowD;
        if (qo < NQ && t <= NT) {
            size_t base = ((size_t)(chunk * NB + b) * NQ + qo) * (NT + 1) + t;
            A_part[base] = accA[r];
            D_part[base] = accD[r];
        }
    }
    spsum += __shfl_xor(spsum, 32);
    if (lane < 32 && q < NQ)
        Sp_part[(size_t)(chunk * NB + b) * NQ + q] = spsum;
}

// ---------------------------------------------------------------------------
// Kernel 2: assemble C[b,q,t]. One block (256 threads) per (b,q);
// wave w reduces chunks [64w, 64w+64), LDS-combine, wave 0 does epilogue.
// ---------------------------------------------------------------------------
__global__ void __launch_bounds__(256)
k_assemble(const float* __restrict__ logits, const int* __restrict__ labels,
           const float* __restrict__ A_part, const float* __restrict__ D_part,
           const float* __restrict__ Sp_part, const int* __restrict__ StmI,
           float* __restrict__ Cout) {
    int bq = blockIdx.x;
    int q = bq % NQ, b = bq / NQ;
    int tid = threadIdx.x, wv = tid >> 6, lane = tid & 63;
    __shared__ float sA[4][64], sD[4][64], sSn[4];

    float At = 0.0f, Dt = 0.0f;
    int t = lane;
    for (int cc = 0; cc < 64; ++cc) {
        int c = wv * 64 + cc;
        size_t base = (size_t)(c * NB + b) * NQ + q;
        if (t <= NT) {
            At += A_part[base * (NT + 1) + t];
            Dt += D_part[base * (NT + 1) + t];
        }
    }
    {   // Sneg: lane-parallel over this wave's 64 chunks
        int c = wv * 64 + lane;
        float sp = Sp_part[(size_t)(c * NB + b) * NQ + q];
        for (int o = 32; o; o >>= 1) sp += __shfl_xor(sp, o);
        if (lane == 0) sSn[wv] = sp;
    }
    sA[wv][lane] = At;
    sD[wv][lane] = Dt;
    __syncthreads();

    if (wv == 0) {
        float At4 = sA[0][lane] + sA[1][lane] + sA[2][lane] + sA[3][lane];
        float Dt4 = sD[0][lane] + sD[1][lane] + sD[2][lane] + sD[3][lane];
        float Sneg = sSn[0] + sSn[1] + sSn[2] + sSn[3];
        float Ssig = __shfl(Dt4, NT);                 // ones-column of D-GEMM

        const float* lg = logits + (size_t)bq * NCLS;
        float x0 = (lane < NCLS) ? lg[lane] : -INFINITY;
        float x1 = (lane + 64 < NCLS) ? lg[lane + 64] : -INFINITY;
        float mx = fmaxf(x0, x1);
        for (int o = 32; o; o >>= 1) mx = fmaxf(mx, __shfl_xor(mx, o));
        float s0 = (lane < NCLS) ? __expf(x0 - mx) : 0.0f;
        float s1 = (lane + 64 < NCLS) ? __expf(x1 - mx) : 0.0f;
        float sum = s0 + s1;
        for (int o = 32; o; o >>= 1) sum += __shfl_xor(sum, o);

        if (lane < NT) {
            int label = labels[b * NT + lane];
            float prob = __expf(lg[label] - mx) / sum;
            float cm = (Sneg - At4) * (1.0f / (float)NHW);
            float stm = (float)StmI[b * NT + lane];
            float cd = 1.0f - (2.0f * Dt4 + 1.0f) / (Ssig + stm + 1.0f);
            float c = 2.0f * (-prob) + 5.0f * cm + 5.0f * cd;
            if (isnan(c)) c = 0.0f;
            Cout[(size_t)bq * NT + lane] = c;
        }
    }
}

// ---------------------------------------------------------------------------
// Kernel 3: linear sum assignment (scipy shortest augmenting path, float64),
// on C[b].T (rows = targets 20, cols = queries 100). One wave per batch.
// ---------------------------------------------------------------------------
__global__ void __launch_bounds__(64)
k_lsa(const float* __restrict__ Cmat, float* __restrict__ out) {
    int b = blockIdx.x;
    int lane = threadIdx.x;
    __shared__ double cost[NT][NQ];
    __shared__ double u[NT], v[NQ], shortest[NQ];
    __shared__ int path[NQ], row4col[NQ], col4row[NT];
    __shared__ unsigned char SR[NT], SC[NQ];
    __shared__ int s_i, s_sink;
    __shared__ double s_minVal;
    __shared__ int qv[NT];

    for (int idx = lane; idx < NT * NQ; idx += 64) {
        int r = idx / NQ, j = idx % NQ;
        cost[r][j] = (double)Cmat[((size_t)b * NQ + j) * NT + r];
    }
    for (int j = lane; j < NQ; j += 64) { v[j] = 0.0; row4col[j] = -1; }
    if (lane < NT) { u[lane] = 0.0; col4row[lane] = -1; }
    __syncthreads();

    for (int cur = 0; cur < NT; ++cur) {
        for (int j = lane; j < NQ; j += 64) { shortest[j] = INFINITY; path[j] = -1; SC[j] = 0; }
        if (lane < NT) SR[lane] = 0;
        if (lane == 0) { s_i = cur; s_minVal = 0.0; s_sink = -1; }
        __syncthreads();

        while (true) {
            int i = s_i;
            double minVal = s_minVal;
            if (lane == 0) SR[i] = 1;
            double ui = u[i];
            double bestv = INFINITY;
            int bestj = NQ;
            for (int j = lane; j < NQ; j += 64) {
                if (!SC[j]) {
                    double d = minVal + cost[i][j] - ui - v[j];
                    if (d < shortest[j]) { shortest[j] = d; path[j] = i; }
                    double sj = shortest[j];
                    if (sj < bestv || (sj == bestv && j < bestj)) { bestv = sj; bestj = j; }
                }
            }
            for (int o = 32; o; o >>= 1) {
                double ov = __shfl_xor(bestv, o);
                int oj = __shfl_xor(bestj, o);
                if (ov < bestv || (ov == bestv && oj < bestj)) { bestv = ov; bestj = oj; }
            }
            __syncthreads();
            if (lane == 0) {
                SC[bestj] = 1;
                s_minVal = bestv;
                if (row4col[bestj] == -1) s_sink = bestj;
                else s_i = row4col[bestj];
            }
            __syncthreads();
            if (s_sink >= 0) break;
        }

        double minVal = s_minVal;
        int sink = s_sink;
        if (lane < NT) {
            if (lane == cur) u[lane] += minVal;
            else if (SR[lane]) u[lane] += minVal - shortest[col4row[lane]];
        }
        for (int j = lane; j < NQ; j += 64) {
            if (SC[j]) v[j] -= minVal - shortest[j];
        }
        __syncthreads();
        if (lane == 0) {
            int j = sink;
            while (true) {
                int i = path[j];
                row4col[j] = i;
                int nj = col4row[i];
                col4row[i] = j;
                j = nj;
                if (i == cur) break;
            }
        }
        __syncthreads();
    }

    if (lane < NT) qv[lane] = col4row[lane];
    __syncthreads();
    if (lane < NT) {
        int my = qv[lane];
        int rank = 0;
#pragma unroll
        for (int t2 = 0; t2 < NT; ++t2) rank += (qv[t2] < my) ? 1 : 0;
        out[NB * NQ * NT + b * NT + rank] = (float)my;              // pred_idx
        out[NB * NQ * NT + NB * NT + b * NT + rank] = (float)lane;  // tgt_idx
    }
}

// ---------------------------------------------------------------------------
extern "C" void kernel_launch(void* const* d_in, const int* in_sizes, int n_in,
                              void* d_out, int out_size, void* d_ws, size_t ws_size,
                              hipStream_t stream) {
    const float* pred_logits = (const float*)d_in[0];   // [4,100,81]
    const float* pred_masks  = (const float*)d_in[1];   // [4,100,256,256]
    const float* tgt_masks   = (const float*)d_in[2];   // [4,20,512,512]
    const int*   tgt_labels  = (const int*)d_in[3];     // [4,20]
    float* out = (float*)d_out;

    char* ws = (char*)d_ws;
    float* A_part  = (float*)ws;                                      // SC2*NB*NQ*21
    float* D_part  = A_part + (size_t)SC2 * NB * NQ * (NT + 1);
    float* Sp_part = D_part + (size_t)SC2 * NB * NQ * (NT + 1);       // SC2*NB*NQ
    int*   StmI    = (int*)(Sp_part + (size_t)SC2 * NB * NQ);         // NB*NT ints

    k_init<<<1, 128, 0, stream>>>(StmI);
    k_main<<<NB * SC2, 256, 0, stream>>>(pred_masks, tgt_masks, A_part, D_part,
                                         Sp_part, StmI);
    k_assemble<<<NB * NQ, 256, 0, stream>>>(pred_logits, tgt_labels, A_part, D_part,
                                            Sp_part, StmI, out);
    k_lsa<<<NB, 64, 0, stream>>>(out, out);
}